// Round 3
// baseline (623.914 us; speedup 1.0000x reference)
//
#include <hip/hip_runtime.h>
#include <hip/hip_bf16.h>

typedef __bf16 bf16;
typedef __bf16 bf16x8 __attribute__((ext_vector_type(8)));
typedef float  f32x4  __attribute__((ext_vector_type(4)));

#define M_DIM 8192
#define N_DIM 4096
#define K_DIM 4096
#define NT    (K_DIM / 64)   // 64 K-tiles of BK=64

#define GLOBAL_AS __attribute__((address_space(1)))
#define LDS_AS    __attribute__((address_space(3)))

// ---------------- conversion kernels (32 B in / 16 B out per thread) ----------------

__global__ __launch_bounds__(256) void cvt_input_bf16(const float4* __restrict__ in,
                                                      bf16x8* __restrict__ out) {
    int idx = blockIdx.x * 256 + threadIdx.x;
    float4 v0 = in[2 * idx];
    float4 v1 = in[2 * idx + 1];
    bf16x8 o;
    o[0] = (bf16)v0.x; o[1] = (bf16)v0.y; o[2] = (bf16)v0.z; o[3] = (bf16)v0.w;
    o[4] = (bf16)v1.x; o[5] = (bf16)v1.y; o[6] = (bf16)v1.z; o[7] = (bf16)v1.w;
    out[idx] = o;
}

__global__ __launch_bounds__(256) void cvt_weight_bf16(const int4* __restrict__ in,
                                                       bf16x8* __restrict__ out) {
    int idx = blockIdx.x * 256 + threadIdx.x;
    int4 v0 = in[2 * idx];
    int4 v1 = in[2 * idx + 1];
    bf16x8 o;
    o[0] = (bf16)(float)v0.x; o[1] = (bf16)(float)v0.y;
    o[2] = (bf16)(float)v0.z; o[3] = (bf16)(float)v0.w;
    o[4] = (bf16)(float)v1.x; o[5] = (bf16)(float)v1.y;
    o[6] = (bf16)(float)v1.z; o[7] = (bf16)(float)v1.w;
    out[idx] = o;
}

// ---------------- main GEMM: 256x256 tile, BK=64, phase-pipelined registers --------
// C[m][n] = sum_k A[m][k]*B[n][k].  8 waves (2M x 4N), wave owns 128x64 output.
// LDS: A,B tiles [256][64] bf16, double-buffered = 128 KiB.  Swizzle: 16B chunk
// c stored at phys chunk c^(row&7); staged via pre-swizzled global source col.
//
// ROUND-3 CHANGE: phases are (mh,kh) quarter-tiles, and each phase's ds_reads
// load the NEXT phase's fragments (afA/afB/bA/bB ping-pong, 64 frag VGPRs).
// Every MFMA's operands were loaded one phase earlier -> the LDS pipe drains
// phase p+1's reads while the matrix pipe runs phase p's MFMAs (true
// cross-pipe overlap; previously serial -> 37% MfmaUtil).
//   ph1 (q=mh0,kh0: afA,bA): load afB<-A[mh1,kh0];          stage A1(t+1)
//   ph2 (q=mh1,kh0: afB,bA): load afA<-A[mh1,kh1], bB<-b[kh1]; stage B1(t+1)
//   ph3 (q=mh1,kh1: afA,bB): load afB<-A[mh0,kh1];          stage B0(t+2)
//   ph4 (q=mh0,kh1: afB,bB): stage A0(t+2); vmcnt(4); BAR (publishes all
//        waves' t+1 stages); wrap-load afA<-A'[mh0,kh0], bA<-b'[kh0] from
//        the other buffer; MFMA.
// One barrier per phase end (hazard proof: every stage is issued >=1 barrier
// after its LDS region's last ds_read; wrap-reads come after vmcnt(4)+BAR so
// cross-wave stage retirement is published).  vmcnt never drained in-loop.

__global__ __launch_bounds__(512, 2) void gemm_bt_256(const bf16* __restrict__ A,
                                                      const bf16* __restrict__ B,
                                                      const float* __restrict__ scales,
                                                      float* __restrict__ C) {
    __shared__ bf16 ldsA[2 * 16384];   // [buf][256][64]
    __shared__ bf16 ldsB[2 * 16384];

    const int tid  = threadIdx.x;
    const int wave = tid >> 6;          // 0..7
    const int lane = tid & 63;
    const int wm   = wave >> 2;         // 0..1  (M)
    const int wn   = wave & 3;          // 0..3  (N)

    // XCD map: XCD x gets a 16m x 4n panel; first-resident 32 blocks form an
    // 8m x 4n chunk (A 4MB + B 8MB L2 fill per round, vs 66MB for n-stripe).
    const int wg = blockIdx.x;
    const int x  = wg & 7;              // XCD (dispatch round-robins blockIdx%8)
    const int c  = wg >> 3;             // 0..63 within XCD
    const int m0 = ((x & 1) * 16 + (c >> 2)) * 256;   // 32 m-tiles
    const int n0 = ((x >> 1) * 4 + (c & 3)) * 256;    // 16 n-tiles

    // staging: thread t covers phys chunk (t&7) of row (t>>3) [+64 for 2nd load]
    const int sr = tid >> 3;                       // 0..63
    const int sc = ((tid & 7) ^ (sr & 7)) * 8;     // pre-swizzled global col (elems)
    const int so = tid * 8;                        // linear LDS dest (elems)

    // fragment addressing
    const int la15 = lane & 15;
    const int lhi  = lane >> 4;                    // 0..3 -> 8-elem k-subchunk
    const int rlow = la15 & 7;
    const int ck0  = ((lhi) ^ rlow) * 8;           // kh=0 chunk, swizzled
    const int ck1  = ((4 + lhi) ^ rlow) * 8;       // kh=1 chunk, swizzled
    const int wrA  = wm * 128;
    const int wrB  = wn * 64;

    f32x4  acc[8][4] = {};
    bf16x8 afA[4], afB[4], bA[4], bB[4];

#define STAGE_A(KT, H) do {                                                              \
    const int _kk = (KT) & (NT - 1);                                                     \
    const int _bb = ((KT) & 1) * 16384;                                                  \
    const bf16* _g0 = A + (size_t)(m0 + (H) * 128 + sr) * K_DIM + _kk * 64 + sc;         \
    __builtin_amdgcn_global_load_lds((GLOBAL_AS const void*)_g0,                         \
        (LDS_AS void*)(ldsA + _bb + (H) * 8192 + so), 16, 0, 0);                         \
    const bf16* _g1 = A + (size_t)(m0 + (H) * 128 + 64 + sr) * K_DIM + _kk * 64 + sc;    \
    __builtin_amdgcn_global_load_lds((GLOBAL_AS const void*)_g1,                         \
        (LDS_AS void*)(ldsA + _bb + (H) * 8192 + 4096 + so), 16, 0, 0);                  \
} while (0)

#define STAGE_B(KT, H) do {                                                              \
    const int _kk = (KT) & (NT - 1);                                                     \
    const int _bb = ((KT) & 1) * 16384;                                                  \
    const bf16* _g0 = B + (size_t)(n0 + (H) * 128 + sr) * K_DIM + _kk * 64 + sc;         \
    __builtin_amdgcn_global_load_lds((GLOBAL_AS const void*)_g0,                         \
        (LDS_AS void*)(ldsB + _bb + (H) * 8192 + so), 16, 0, 0);                         \
    const bf16* _g1 = B + (size_t)(n0 + (H) * 128 + 64 + sr) * K_DIM + _kk * 64 + sc;    \
    __builtin_amdgcn_global_load_lds((GLOBAL_AS const void*)_g1,                         \
        (LDS_AS void*)(ldsB + _bb + (H) * 8192 + 4096 + so), 16, 0, 0);                  \
} while (0)

// load A quarter (MH half of wave's rows, K-half KH) -> DST[0..3]
#define LD_A(MH, KH, DST, BO) do {                                                       \
    _Pragma("unroll")                                                                    \
    for (int _i = 0; _i < 4; ++_i) {                                                     \
        const int _r = (BO) + (wrA + (MH) * 64 + _i * 16 + la15) * 64;                   \
        DST[_i] = *(const bf16x8*)(ldsA + _r + ((KH) ? ck1 : ck0));                      \
    }                                                                                    \
} while (0)

// load B K-half KH (all 4 col-frags) -> DST[0..3]
#define LD_B(KH, DST, BO) do {                                                           \
    _Pragma("unroll")                                                                    \
    for (int _j = 0; _j < 4; ++_j) {                                                     \
        const int _r = (BO) + (wrB + _j * 16 + la15) * 64;                               \
        DST[_j] = *(const bf16x8*)(ldsB + _r + ((KH) ? ck1 : ck0));                      \
    }                                                                                    \
} while (0)

// 16 independent MFMAs: acc[I0+i][j] += AF[i] * BF[j]
#define MMA_Q(I0, AF, BF) do {                                                           \
    __builtin_amdgcn_s_setprio(1);                                                       \
    _Pragma("unroll")                                                                    \
    for (int _i = 0; _i < 4; ++_i) {                                                     \
        _Pragma("unroll")                                                                \
        for (int _j = 0; _j < 4; ++_j) {                                                 \
            acc[(I0) + _i][_j] = __builtin_amdgcn_mfma_f32_16x16x32_bf16(                \
                AF[_i], BF[_j], acc[(I0) + _i][_j], 0, 0, 0);                            \
        }                                                                                \
    }                                                                                    \
    __builtin_amdgcn_s_setprio(0);                                                       \
} while (0)

#define BAR() __builtin_amdgcn_s_barrier()

    // ---- prologue: tile0 fully + tile1 {B0,A0} in flight; preload ph1 operands ----
    STAGE_A(0, 0); STAGE_B(0, 0); STAGE_A(0, 1); STAGE_B(0, 1);
    STAGE_B(1, 0); STAGE_A(1, 0);
    asm volatile("s_waitcnt vmcnt(4)" ::: "memory");   // tile0 landed (this wave)
    BAR();                                             // ...published (all waves)
    LD_A(0, 0, afA, 0);
    LD_B(0, bA, 0);

    for (int t = 0; t < NT; ++t) {
        const int bo = (t & 1) * 16384;
        const int bn = bo ^ 16384;

        // ph1: MFMA(mh0,kh0)=afA,bA ; prefetch afB<-A[mh1,kh0] ; stage A1(t+1)
        STAGE_A(t + 1, 1);
        LD_A(1, 0, afB, bo);
        MMA_Q(0, afA, bA);
        BAR();

        // ph2: MFMA(mh1,kh0)=afB,bA ; prefetch afA<-A[mh1,kh1], bB<-b[kh1] ; stage B1(t+1)
        STAGE_B(t + 1, 1);
        LD_A(1, 1, afA, bo);
        LD_B(1, bB, bo);
        MMA_Q(4, afB, bA);
        BAR();

        // ph3: MFMA(mh1,kh1)=afA,bB ; prefetch afB<-A[mh0,kh1] ; stage B0(t+2)
        STAGE_B(t + 2, 0);
        LD_A(0, 1, afB, bo);
        MMA_Q(4, afA, bB);
        BAR();

        // ph4: MFMA(mh0,kh1)=afB,bB ; stage A0(t+2); vmcnt(4)+BAR publishes tile t+1;
        //      wrap-prefetch afA<-A'[mh0,kh0], bA<-b'[kh0] from other buffer
        STAGE_A(t + 2, 0);
        asm volatile("s_waitcnt vmcnt(4)" ::: "memory");  // all t+1 stages retired (this wave)
        BAR();                                            // ...and published (all waves)
        LD_A(0, 0, afA, bn);
        LD_B(0, bA, bn);
        MMA_Q(0, afB, bB);
        BAR();
    }

    asm volatile("s_waitcnt vmcnt(0)" ::: "memory");  // drain tail stages before exit

    // ---- epilogue: C/D layout col = lane&15 (N), row = (lane>>4)*4 + reg (M) ----
    const int crow = lhi * 4;
#pragma unroll
    for (int j = 0; j < 4; ++j) {
        const int col = n0 + wrB + j * 16 + la15;
        const float s = scales[col];
#pragma unroll
        for (int i = 0; i < 8; ++i) {
            const int rowb = m0 + wrA + i * 16 + crow;
#pragma unroll
            for (int r = 0; r < 4; ++r)
                C[(size_t)(rowb + r) * N_DIM + col] = acc[i][j][r] * s;
        }
    }

#undef STAGE_A
#undef STAGE_B
#undef LD_A
#undef LD_B
#undef MMA_Q
#undef BAR
}

// ---------------- fallback: fused conversion staging (no workspace needed) ----------------

__global__ __launch_bounds__(256, 2) void gemm_fused(const float* __restrict__ A,
                                                     const int* __restrict__ B,
                                                     const float* __restrict__ scales,
                                                     float* __restrict__ C) {
    __shared__ bf16 lds_a[128 * 32];
    __shared__ bf16 lds_b[128 * 32];

    const int tid  = threadIdx.x;
    const int wave = tid >> 6;
    const int lane = tid & 63;
    const int m0 = blockIdx.y * 128;
    const int n0 = blockIdx.x * 128;
    const int wm = (wave >> 1) * 64;
    const int wn = (wave & 1) * 64;

    const int sr = tid >> 1;
    const int sc = (tid & 1) * 16;

    const int la = lane & 15;
    const int lk = (lane >> 4) * 8;

    f32x4 acc[4][4] = {};

    for (int k0 = 0; k0 < K_DIM; k0 += 32) {
        __syncthreads();
        {
            const float* ga = A + (size_t)(m0 + sr) * K_DIM + k0 + sc;
            float4 v0 = *(const float4*)(ga + 0);
            float4 v1 = *(const float4*)(ga + 4);
            float4 v2 = *(const float4*)(ga + 8);
            float4 v3 = *(const float4*)(ga + 12);
            bf16x8 p0, p1;
            p0[0]=(bf16)v0.x; p0[1]=(bf16)v0.y; p0[2]=(bf16)v0.z; p0[3]=(bf16)v0.w;
            p0[4]=(bf16)v1.x; p0[5]=(bf16)v1.y; p0[6]=(bf16)v1.z; p0[7]=(bf16)v1.w;
            p1[0]=(bf16)v2.x; p1[1]=(bf16)v2.y; p1[2]=(bf16)v2.z; p1[3]=(bf16)v2.w;
            p1[4]=(bf16)v3.x; p1[5]=(bf16)v3.y; p1[6]=(bf16)v3.z; p1[7]=(bf16)v3.w;
            *(bf16x8*)(lds_a + sr * 32 + sc)     = p0;
            *(bf16x8*)(lds_a + sr * 32 + sc + 8) = p1;
        }
        {
            const int* gb = B + (size_t)(n0 + sr) * K_DIM + k0 + sc;
            int4 v0 = *(const int4*)(gb + 0);
            int4 v1 = *(const int4*)(gb + 4);
            int4 v2 = *(const int4*)(gb + 8);
            int4 v3 = *(const int4*)(gb + 12);
            bf16x8 p0, p1;
            p0[0]=(bf16)(float)v0.x; p0[1]=(bf16)(float)v0.y; p0[2]=(bf16)(float)v0.z; p0[3]=(bf16)(float)v0.w;
            p0[4]=(bf16)(float)v1.x; p0[5]=(bf16)(float)v1.y; p0[6]=(bf16)(float)v1.z; p0[7]=(bf16)(float)v1.w;
            p1[0]=(bf16)(float)v2.x; p1[1]=(bf16)(float)v2.y; p1[2]=(bf16)(float)v2.z; p1[3]=(bf16)(float)v2.w;
            p1[4]=(bf16)(float)v3.x; p1[5]=(bf16)(float)v3.y; p1[6]=(bf16)(float)v3.z; p1[7]=(bf16)(float)v3.w;
            *(bf16x8*)(lds_b + sr * 32 + sc)     = p0;
            *(bf16x8*)(lds_b + sr * 32 + sc + 8) = p1;
        }
        __syncthreads();

        bf16x8 af[4], bfg[4];
#pragma unroll
        for (int i = 0; i < 4; ++i)
            af[i] = *(const bf16x8*)(lds_a + (wm + i * 16 + la) * 32 + lk);
#pragma unroll
        for (int j = 0; j < 4; ++j)
            bfg[j] = *(const bf16x8*)(lds_b + (wn + j * 16 + la) * 32 + lk);
#pragma unroll
        for (int i = 0; i < 4; ++i)
#pragma unroll
            for (int j = 0; j < 4; ++j)
                acc[i][j] = __builtin_amdgcn_mfma_f32_16x16x32_bf16(af[i], bfg[j], acc[i][j], 0, 0, 0);
    }

    const int crow = (lane >> 4) * 4;
#pragma unroll
    for (int j = 0; j < 4; ++j) {
        const int col = n0 + wn + j * 16 + la;
        const float s = scales[col];
#pragma unroll
        for (int i = 0; i < 4; ++i) {
            const int rowb = m0 + wm + i * 16 + crow;
#pragma unroll
            for (int r = 0; r < 4; ++r)
                C[(size_t)(rowb + r) * N_DIM + col] = acc[i][j][r] * s;
        }
    }
}

// ---------------- launch ----------------

extern "C" void kernel_launch(void* const* d_in, const int* in_sizes, int n_in,
                              void* d_out, int out_size, void* d_ws, size_t ws_size,
                              hipStream_t stream) {
    const float* input  = (const float*)d_in[0];   // [M, K] fp32
    const int*   weight = (const int*)d_in[1];     // [N, K] int32 (int8 values)
    const float* scales = (const float*)d_in[2];   // [N] fp32
    float* out = (float*)d_out;                    // [M, N] fp32

    const size_t needA = (size_t)M_DIM * K_DIM * sizeof(bf16);   // 64 MiB
    const size_t needB = (size_t)N_DIM * K_DIM * sizeof(bf16);   // 32 MiB

    if (ws_size >= needA + needB) {
        bf16* Abf = (bf16*)d_ws;
        bf16* Bbf = (bf16*)((char*)d_ws + needA);
        cvt_input_bf16<<<(M_DIM * (size_t)K_DIM / 8) / 256, 256, 0, stream>>>(
            (const float4*)input, (bf16x8*)Abf);
        cvt_weight_bf16<<<(N_DIM * (size_t)K_DIM / 8) / 256, 256, 0, stream>>>(
            (const int4*)weight, (bf16x8*)Bbf);
        gemm_bt_256<<<(M_DIM / 256) * (N_DIM / 256), 512, 0, stream>>>(Abf, Bbf, scales, out);
    } else {
        dim3 grid(N_DIM / 128, M_DIM / 128);
        gemm_fused<<<grid, 256, 0, stream>>>(input, weight, scales, out);
    }
}

// Round 4
// 548.558 us; speedup vs baseline: 1.1374x; 1.1374x over previous
//
#include <hip/hip_runtime.h>
#include <hip/hip_bf16.h>

typedef __bf16 bf16;
typedef __bf16 bf16x8 __attribute__((ext_vector_type(8)));
typedef float  f32x16 __attribute__((ext_vector_type(16)));
typedef float  f32x4  __attribute__((ext_vector_type(4)));

#define M_DIM 8192
#define N_DIM 4096
#define K_DIM 4096
#define NT    (K_DIM / 64)   // 64 K-tiles of BK=64

#define GLOBAL_AS __attribute__((address_space(1)))
#define LDS_AS    __attribute__((address_space(3)))

// ---------------- merged conversion kernel (one launch for A and B) ----------------
// blocks [0, 16384): A fp32->bf16 ; blocks [16384, 24576): W int32->bf16.
// 32 B in / 16 B out per thread, fully coalesced.

#define CVT_A_BLOCKS 16384   // 8192*4096/8/256
#define CVT_B_BLOCKS 8192    // 4096*4096/8/256

__global__ __launch_bounds__(256) void cvt_both(const float4* __restrict__ a_in,
                                                bf16x8* __restrict__ a_out,
                                                const int4* __restrict__ b_in,
                                                bf16x8* __restrict__ b_out) {
    const int b = blockIdx.x;
    if (b < CVT_A_BLOCKS) {
        int idx = b * 256 + threadIdx.x;
        float4 v0 = a_in[2 * idx];
        float4 v1 = a_in[2 * idx + 1];
        bf16x8 o;
        o[0] = (bf16)v0.x; o[1] = (bf16)v0.y; o[2] = (bf16)v0.z; o[3] = (bf16)v0.w;
        o[4] = (bf16)v1.x; o[5] = (bf16)v1.y; o[6] = (bf16)v1.z; o[7] = (bf16)v1.w;
        a_out[idx] = o;
    } else {
        int idx = (b - CVT_A_BLOCKS) * 256 + threadIdx.x;
        int4 v0 = b_in[2 * idx];
        int4 v1 = b_in[2 * idx + 1];
        bf16x8 o;
        o[0] = (bf16)(float)v0.x; o[1] = (bf16)(float)v0.y;
        o[2] = (bf16)(float)v0.z; o[3] = (bf16)(float)v0.w;
        o[4] = (bf16)(float)v1.x; o[5] = (bf16)(float)v1.y;
        o[6] = (bf16)(float)v1.z; o[7] = (bf16)(float)v1.w;
        b_out[idx] = o;
    }
}

// ---------------- main GEMM: 256x256 tile, BK=64, r2 schedule + 32x32x16 MFMA ------
// C[m][n] = sum_k A[m][k]*B[n][k].  8 waves (2M x 4N), wave owns 128x64 output.
// LDS: A,B tiles [256][64] bf16, double-buffered = 128 KiB.  Swizzle: 16B chunk
// c stored at phys chunk c^(row&7); staged via pre-swizzled global source col.
//
// ROUND-4 CHANGE: mfma_f32_32x32x16_bf16 (measured pipe 2495 TF vs 16x16's
// 2075 -> +20% at equal util; half the MFMA instruction count).  Fragment
// geometry: wave = 4 m-frags x 2 n-frags of 32; per K=64: 4 k-steps.
// A/B input layout: lane l -> (row = l&31, k = (l>>5)*8 + e)  [analog of the
// verified 16x16x32 layout].  C/D: col = lane&31, row = (r&3)+8*(r>>2)+
// 4*(lane>>5)  [m74/m101-verified].
// Phase/stage/barrier/vmcnt structure is r2 verbatim (best measured: 888 TF):
//   ph1: read A-mh0(8) + B-nh0(4); stage A1(t+1); BAR; 8 MFMA (q 0,0); BAR
//   ph2: read B-nh1(4);            stage B1(t+1); BAR; 8 MFMA (q 0,1); BAR
//   ph3: read A-mh1(8);            stage B0(t+2); BAR; 8 MFMA (q 1,1); BAR
//   ph4:                           stage A0(t+2); BAR; 8 MFMA (q 1,0); vmcnt(4); BAR
// Region proof unchanged: each stage lands >=1 barrier after its region's
// last ds_read; vmcnt(4) at ph4 retires all of tile t+1 (8 newer loads
// outstanding at the wait, 12 total, oldest 8 = t+1's A0,B0,A1,B1).

__global__ __launch_bounds__(512, 2) void gemm_bt_256(const bf16* __restrict__ A,
                                                      const bf16* __restrict__ B,
                                                      const float* __restrict__ scales,
                                                      float* __restrict__ C) {
    __shared__ bf16 ldsA[2 * 16384];   // [buf][256][64]
    __shared__ bf16 ldsB[2 * 16384];

    const int tid  = threadIdx.x;
    const int wave = tid >> 6;          // 0..7
    const int lane = tid & 63;
    const int wm   = wave >> 2;         // 0..1  (M)
    const int wn   = wave & 3;          // 0..3  (N)

    // XCD map (r3, proven FETCH 553->201 GB): XCD x gets a 16m x 4n panel;
    // resident 32 blocks form an 8m x 4n chunk (A 4MB + B 8MB per round).
    const int wg = blockIdx.x;
    const int x  = wg & 7;              // XCD (dispatch round-robins blockIdx%8)
    const int c  = wg >> 3;             // 0..63 within XCD
    const int m0 = ((x & 1) * 16 + (c >> 2)) * 256;   // 32 m-tiles
    const int n0 = ((x >> 1) * 4 + (c & 3)) * 256;    // 16 n-tiles

    // staging: thread t covers phys chunk (t&7) of row (t>>3) [+64 for 2nd load]
    const int sr = tid >> 3;                       // 0..63
    const int sc = ((tid & 7) ^ (sr & 7)) * 8;     // pre-swizzled global col (elems)
    const int so = tid * 8;                        // linear LDS dest (elems)

    // fragment addressing (32x32x16)
    const int l31 = lane & 31;
    const int hi2 = lane >> 5;                     // 0..1 -> 8-elem k-subchunk
    const int r7  = l31 & 7;
    // swizzled chunk offset (elements) for k-step ks: chunk = (ks*2 + hi2) ^ (row&7),
    // and row&7 == l31&7 for all frag rows (bases are multiples of 32).
    int cks[4];
#pragma unroll
    for (int ks = 0; ks < 4; ++ks) cks[ks] = ((ks * 2 + hi2) ^ r7) * 8;

    const int wrA = wm * 128;
    const int wrB = wn * 64;

    f32x16 acc[4][2] = {};   // [m-frag 0..3][n-frag 0..1]
    bf16x8 af[2][4], bf0[4], bf1[4];

#define STAGE_A(KT, H) do {                                                              \
    const int _kk = (KT) & (NT - 1);                                                     \
    const int _bb = ((KT) & 1) * 16384;                                                  \
    const bf16* _g0 = A + (size_t)(m0 + (H) * 128 + sr) * K_DIM + _kk * 64 + sc;         \
    __builtin_amdgcn_global_load_lds((GLOBAL_AS const void*)_g0,                         \
        (LDS_AS void*)(ldsA + _bb + (H) * 8192 + so), 16, 0, 0);                         \
    const bf16* _g1 = A + (size_t)(m0 + (H) * 128 + 64 + sr) * K_DIM + _kk * 64 + sc;    \
    __builtin_amdgcn_global_load_lds((GLOBAL_AS const void*)_g1,                         \
        (LDS_AS void*)(ldsA + _bb + (H) * 8192 + 4096 + so), 16, 0, 0);                  \
} while (0)

#define STAGE_B(KT, H) do {                                                              \
    const int _kk = (KT) & (NT - 1);                                                     \
    const int _bb = ((KT) & 1) * 16384;                                                  \
    const bf16* _g0 = B + (size_t)(n0 + (H) * 128 + sr) * K_DIM + _kk * 64 + sc;         \
    __builtin_amdgcn_global_load_lds((GLOBAL_AS const void*)_g0,                         \
        (LDS_AS void*)(ldsB + _bb + (H) * 8192 + so), 16, 0, 0);                         \
    const bf16* _g1 = B + (size_t)(n0 + (H) * 128 + 64 + sr) * K_DIM + _kk * 64 + sc;    \
    __builtin_amdgcn_global_load_lds((GLOBAL_AS const void*)_g1,                         \
        (LDS_AS void*)(ldsB + _bb + (H) * 8192 + 4096 + so), 16, 0, 0);                  \
} while (0)

// A frags for m-half MH (rows wrA+MH*64 .. +127): af[mf][ks], 8 x ds_read_b128
#define LD_A(MH, BO) do {                                                                \
    _Pragma("unroll")                                                                    \
    for (int _mf = 0; _mf < 2; ++_mf) {                                                  \
        const int _row = wrA + (MH) * 64 + _mf * 32 + l31;                               \
        _Pragma("unroll")                                                                \
        for (int _ks = 0; _ks < 4; ++_ks)                                                \
            af[_mf][_ks] = *(const bf16x8*)(ldsA + (BO) + _row * 64 + cks[_ks]);         \
    }                                                                                    \
} while (0)

// B frags for n-half NH (rows wrB+NH*32 .. +31): DST[ks], 4 x ds_read_b128
#define LD_B(NH, DST, BO) do {                                                           \
    const int _row = wrB + (NH) * 32 + l31;                                              \
    _Pragma("unroll")                                                                    \
    for (int _ks = 0; _ks < 4; ++_ks)                                                    \
        DST[_ks] = *(const bf16x8*)(ldsB + (BO) + _row * 64 + cks[_ks]);                 \
} while (0)

// 8 MFMAs: quadrant (MH, NH), acc[MH*2+mf][NH] over 4 k-steps
#define MMA_Q(MH, NH, BF) do {                                                           \
    __builtin_amdgcn_s_setprio(1);                                                       \
    _Pragma("unroll")                                                                    \
    for (int _ks = 0; _ks < 4; ++_ks) {                                                  \
        _Pragma("unroll")                                                                \
        for (int _mf = 0; _mf < 2; ++_mf) {                                              \
            acc[(MH) * 2 + _mf][NH] = __builtin_amdgcn_mfma_f32_32x32x16_bf16(           \
                af[_mf][_ks], BF[_ks], acc[(MH) * 2 + _mf][NH], 0, 0, 0);                \
        }                                                                                \
    }                                                                                    \
    __builtin_amdgcn_s_setprio(0);                                                       \
} while (0)

#define BAR() __builtin_amdgcn_s_barrier()

    // ---- prologue: tile0 fully + tile1 {B0,A0} in flight ----
    STAGE_A(0, 0); STAGE_B(0, 0); STAGE_A(0, 1); STAGE_B(0, 1);
    STAGE_B(1, 0); STAGE_A(1, 0);
    asm volatile("s_waitcnt vmcnt(4)" ::: "memory");   // tile0 landed (this wave)
    BAR();                                             // ...published (all waves)

    for (int t = 0; t < NT; ++t) {
        const int bo = (t & 1) * 16384;

        // ph1: reads A-mh0 + B-nh0 ; stage A1(t+1) ; MFMA quadrant (0,0)
        LD_A(0, bo);
        LD_B(0, bf0, bo);
        STAGE_A(t + 1, 1);
        BAR();
        MMA_Q(0, 0, bf0);
        BAR();

        // ph2: reads B-nh1 ; stage B1(t+1) ; MFMA quadrant (0,1)
        LD_B(1, bf1, bo);
        STAGE_B(t + 1, 1);
        BAR();
        MMA_Q(0, 1, bf1);
        BAR();

        // ph3: reads A-mh1 ; stage B0(t+2) ; MFMA quadrant (1,1)
        LD_A(1, bo);
        STAGE_B(t + 2, 0);
        BAR();
        MMA_Q(1, 1, bf1);
        BAR();

        // ph4: stage A0(t+2) ; MFMA quadrant (1,0) ; vmcnt(4) -> tile t+1 resident
        STAGE_A(t + 2, 0);
        BAR();
        MMA_Q(1, 0, bf0);
        asm volatile("s_waitcnt vmcnt(4)" ::: "memory");
        BAR();
    }

    asm volatile("s_waitcnt vmcnt(0)" ::: "memory");  // drain tail stages before exit

    // ---- epilogue: C/D layout col = lane&31 (N), row = (r&3)+8*(r>>2)+4*hi2 (M) ----
#pragma unroll
    for (int g = 0; g < 2; ++g) {
        const int col = n0 + wrB + g * 32 + l31;
        const float s = scales[col];
#pragma unroll
        for (int f = 0; f < 4; ++f) {
            const int mbase = m0 + wrA + f * 32 + 4 * hi2;
#pragma unroll
            for (int r = 0; r < 16; ++r) {
                const int row = mbase + (r & 3) + 8 * (r >> 2);
                C[(size_t)row * N_DIM + col] = acc[f][g][r] * s;
            }
        }
    }

#undef STAGE_A
#undef STAGE_B
#undef LD_A
#undef LD_B
#undef MMA_Q
#undef BAR
}

// ---------------- fallback: fused conversion staging (no workspace needed) ----------------

__global__ __launch_bounds__(256, 2) void gemm_fused(const float* __restrict__ A,
                                                     const int* __restrict__ B,
                                                     const float* __restrict__ scales,
                                                     float* __restrict__ C) {
    __shared__ bf16 lds_a[128 * 32];
    __shared__ bf16 lds_b[128 * 32];

    const int tid  = threadIdx.x;
    const int wave = tid >> 6;
    const int lane = tid & 63;
    const int m0 = blockIdx.y * 128;
    const int n0 = blockIdx.x * 128;
    const int wm = (wave >> 1) * 64;
    const int wn = (wave & 1) * 64;

    const int sr = tid >> 1;
    const int sc = (tid & 1) * 16;

    const int la = lane & 15;
    const int lk = (lane >> 4) * 8;

    f32x4 acc[4][4] = {};

    for (int k0 = 0; k0 < K_DIM; k0 += 32) {
        __syncthreads();
        {
            const float* ga = A + (size_t)(m0 + sr) * K_DIM + k0 + sc;
            float4 v0 = *(const float4*)(ga + 0);
            float4 v1 = *(const float4*)(ga + 4);
            float4 v2 = *(const float4*)(ga + 8);
            float4 v3 = *(const float4*)(ga + 12);
            bf16x8 p0, p1;
            p0[0]=(bf16)v0.x; p0[1]=(bf16)v0.y; p0[2]=(bf16)v0.z; p0[3]=(bf16)v0.w;
            p0[4]=(bf16)v1.x; p0[5]=(bf16)v1.y; p0[6]=(bf16)v1.z; p0[7]=(bf16)v1.w;
            p1[0]=(bf16)v2.x; p1[1]=(bf16)v2.y; p1[2]=(bf16)v2.z; p1[3]=(bf16)v2.w;
            p1[4]=(bf16)v3.x; p1[5]=(bf16)v3.y; p1[6]=(bf16)v3.z; p1[7]=(bf16)v3.w;
            *(bf16x8*)(lds_a + sr * 32 + sc)     = p0;
            *(bf16x8*)(lds_a + sr * 32 + sc + 8) = p1;
        }
        {
            const int* gb = B + (size_t)(n0 + sr) * K_DIM + k0 + sc;
            int4 v0 = *(const int4*)(gb + 0);
            int4 v1 = *(const int4*)(gb + 4);
            int4 v2 = *(const int4*)(gb + 8);
            int4 v3 = *(const int4*)(gb + 12);
            bf16x8 p0, p1;
            p0[0]=(bf16)(float)v0.x; p0[1]=(bf16)(float)v0.y; p0[2]=(bf16)(float)v0.z; p0[3]=(bf16)(float)v0.w;
            p0[4]=(bf16)(float)v1.x; p0[5]=(bf16)(float)v1.y; p0[6]=(bf16)(float)v1.z; p0[7]=(bf16)(float)v1.w;
            p1[0]=(bf16)(float)v2.x; p1[1]=(bf16)(float)v2.y; p1[2]=(bf16)(float)v2.z; p1[3]=(bf16)(float)v2.w;
            p1[4]=(bf16)(float)v3.x; p1[5]=(bf16)(float)v3.y; p1[6]=(bf16)(float)v3.z; p1[7]=(bf16)(float)v3.w;
            *(bf16x8*)(lds_b + sr * 32 + sc)     = p0;
            *(bf16x8*)(lds_b + sr * 32 + sc + 8) = p1;
        }
        __syncthreads();

        bf16x8 af[4], bfg[4];
#pragma unroll
        for (int i = 0; i < 4; ++i)
            af[i] = *(const bf16x8*)(lds_a + (wm + i * 16 + la) * 32 + lk);
#pragma unroll
        for (int j = 0; j < 4; ++j)
            bfg[j] = *(const bf16x8*)(lds_b + (wn + j * 16 + la) * 32 + lk);
#pragma unroll
        for (int i = 0; i < 4; ++i)
#pragma unroll
            for (int j = 0; j < 4; ++j)
                acc[i][j] = __builtin_amdgcn_mfma_f32_16x16x32_bf16(af[i], bfg[j], acc[i][j], 0, 0, 0);
    }

    const int crow = (lane >> 4) * 4;
#pragma unroll
    for (int j = 0; j < 4; ++j) {
        const int col = n0 + wn + j * 16 + la;
        const float s = scales[col];
#pragma unroll
        for (int i = 0; i < 4; ++i) {
            const int rowb = m0 + wm + i * 16 + crow;
#pragma unroll
            for (int r = 0; r < 4; ++r)
                C[(size_t)(rowb + r) * N_DIM + col] = acc[i][j][r] * s;
        }
    }
}

// ---------------- launch ----------------

extern "C" void kernel_launch(void* const* d_in, const int* in_sizes, int n_in,
                              void* d_out, int out_size, void* d_ws, size_t ws_size,
                              hipStream_t stream) {
    const float* input  = (const float*)d_in[0];   // [M, K] fp32
    const int*   weight = (const int*)d_in[1];     // [N, K] int32 (int8 values)
    const float* scales = (const float*)d_in[2];   // [N] fp32
    float* out = (float*)d_out;                    // [M, N] fp32

    const size_t needA = (size_t)M_DIM * K_DIM * sizeof(bf16);   // 64 MiB
    const size_t needB = (size_t)N_DIM * K_DIM * sizeof(bf16);   // 32 MiB

    if (ws_size >= needA + needB) {
        bf16* Abf = (bf16*)d_ws;
        bf16* Bbf = (bf16*)((char*)d_ws + needA);
        cvt_both<<<CVT_A_BLOCKS + CVT_B_BLOCKS, 256, 0, stream>>>(
            (const float4*)input, (bf16x8*)Abf, (const int4*)weight, (bf16x8*)Bbf);
        gemm_bt_256<<<(M_DIM / 256) * (N_DIM / 256), 512, 0, stream>>>(Abf, Bbf, scales, out);
    } else {
        dim3 grid(N_DIM / 128, M_DIM / 128);
        gemm_fused<<<grid, 256, 0, stream>>>(input, weight, scales, out);
    }
}